// Round 1
// baseline (193.773 us; speedup 1.0000x reference)
//
#include <hip/hip_runtime.h>
#include <math.h>

#define NN 4096
#define CC 64

constexpr float K_MARGIN = 0.4f;
constexpr float K_GAMMA  = 80.0f;
// Algebraic bounds on the logits given sim = tanh(.) in (-1, 1):
//   logit_p = -max(1.4 - s, 0) * (s - 0.6) * 80  <  2.4 * 1.6 * 80 = 307.2
//   logit_n =  max(s + 0.4, 0) * (s - 0.4) * 80  <  1.4 * 0.6 * 80 =  67.2
constexpr float M_P = 307.2f;
constexpr float M_N = 67.2f;

// ws layout: float acc[4] = {s_p, c_p, s_n, c_n} at byte 0; int ids[4096] at byte 256.

__global__ void ids_init_kernel(const float* __restrict__ clusters,
                                int* __restrict__ ids, float* __restrict__ acc) {
    int i = blockIdx.x * blockDim.x + threadIdx.x;
    if (i < 4) acc[i] = 0.0f;          // zero accumulators (ws is poisoned 0xAA)
    if (i < NN) {
        const float* row = clusters + i * CC;
        int id = 0;
        #pragma unroll
        for (int c = 0; c < CC; ++c) {
            if (row[c] > 0.5f) id = c; // one-hot -> exactly one entry == 1.0
        }
        ids[i] = id;
    }
}

__global__ __launch_bounds__(256) void circle_main_kernel(
        const float* __restrict__ sim, const int* __restrict__ ids,
        float* __restrict__ acc) {
    float s_p = 0.f, c_p = 0.f, s_n = 0.f, c_n = 0.f;
    const int n4 = NN * NN / 4;
    const int stride = gridDim.x * blockDim.x;
    for (int idx = blockIdx.x * blockDim.x + (int)threadIdx.x; idx < n4; idx += stride) {
        const int lin = idx << 2;
        const int i  = lin >> 12;        // row (N = 4096 = 2^12)
        const int j0 = lin & (NN - 1);   // col of first of 4 elements
        if (j0 + 3 <= i) continue;       // whole chunk in lower triangle / diag: no load
        const float4 s4 = reinterpret_cast<const float4*>(sim)[idx];
        const int4  id4 = reinterpret_cast<const int4*>(ids)[j0 >> 2];
        const int   idi = ids[i];
        const float sv[4] = {s4.x, s4.y, s4.z, s4.w};
        const int   jv[4] = {id4.x, id4.y, id4.z, id4.w};
        #pragma unroll
        for (int k = 0; k < 4; ++k) {
            const int   j     = j0 + k;
            const bool  valid = (j > i);
            const bool  same  = (jv[k] == idi);
            const float s     = sv[k];
            const float lp = -fmaxf(1.0f + K_MARGIN - s, 0.0f) * (s - (1.0f - K_MARGIN)) * K_GAMMA;
            const float ln =  fmaxf(s + K_MARGIN, 0.0f) * (s - K_MARGIN) * K_GAMMA;
            const float ep = __expf(lp - M_P);
            const float en = __expf(ln - M_N);
            if (valid && same)  { s_p += ep; c_p += 1.0f; }
            if (valid && !same) { s_n += en; c_n += 1.0f; }
        }
    }
    // wave (64-lane) butterfly reduction
    #pragma unroll
    for (int off = 32; off > 0; off >>= 1) {
        s_p += __shfl_xor(s_p, off);
        c_p += __shfl_xor(c_p, off);
        s_n += __shfl_xor(s_n, off);
        c_n += __shfl_xor(c_n, off);
    }
    __shared__ float red[4][4];
    const int wave = threadIdx.x >> 6;
    const int lane = threadIdx.x & 63;
    if (lane == 0) {
        red[wave][0] = s_p; red[wave][1] = c_p;
        red[wave][2] = s_n; red[wave][3] = c_n;
    }
    __syncthreads();
    if (threadIdx.x == 0) {
        float a = 0.f, b = 0.f, c = 0.f, d = 0.f;
        #pragma unroll
        for (int w = 0; w < 4; ++w) {
            a += red[w][0]; b += red[w][1]; c += red[w][2]; d += red[w][3];
        }
        atomicAdd(&acc[0], a);
        atomicAdd(&acc[1], b);
        atomicAdd(&acc[2], c);
        atomicAdd(&acc[3], d);
    }
}

__device__ inline float softplus_f(float x) {
    // stable: max(x,0) + log1p(exp(-|x|)); maps -inf -> 0
    return fmaxf(x, 0.0f) + log1pf(expf(-fabsf(x)));
}

__global__ void circle_final_kernel(const float* __restrict__ acc,
                                    float* __restrict__ out) {
    const float s_p = acc[0], c_p = acc[1], s_n = acc[2], c_n = acc[3];
    const float lse_p = logf(s_p) + M_P;   // -inf if no positive pairs
    const float lse_n = logf(s_n) + M_N;
    // prob == 1.0 exactly on positive pairs (one-hot dot), 0.0 on negatives
    const float wp_mean = c_p / fmaxf(c_p, 1.0f);
    const float wn_mean = 0.0f / fmaxf(c_n, 1.0f);
    out[0] = wp_mean * softplus_f(lse_p) + wn_mean * softplus_f(lse_n);
}

extern "C" void kernel_launch(void* const* d_in, const int* in_sizes, int n_in,
                              void* d_out, int out_size, void* d_ws, size_t ws_size,
                              hipStream_t stream) {
    const float* sim      = (const float*)d_in[0];
    const float* clusters = (const float*)d_in[1];
    float* out = (float*)d_out;
    float* acc = (float*)d_ws;
    int*   ids = (int*)((char*)d_ws + 256);

    ids_init_kernel<<<(NN + 255) / 256, 256, 0, stream>>>(clusters, ids, acc);
    circle_main_kernel<<<2048, 256, 0, stream>>>(sim, ids, acc);
    circle_final_kernel<<<1, 1, 0, stream>>>(acc, out);
}

// Round 4
// 97.510 us; speedup vs baseline: 1.9872x; 1.9872x over previous
//
#include <hip/hip_runtime.h>
#include <math.h>

#define NN 4096
#define CC 64

constexpr float K_MARGIN = 0.4f;
constexpr float K_GAMMA  = 80.0f;
// Algebraic bounds on the logits given sim = tanh(.) in (-1, 1):
//   logit_p = -max(1.4 - s, 0) * (s - 0.6) * 80  <  2.4 * 1.6 * 80 = 307.2
//   logit_n =  max(s + 0.4, 0) * (s - 0.4) * 80  <  1.4 * 0.6 * 80 =  67.2
constexpr float M_P = 307.2f;
constexpr float M_N = 67.2f;

// ws layout: int ids[4096] at byte 0 (16 KB); float4 partials[2048] at byte 16384 (32 KB).

__global__ __launch_bounds__(256) void ids_kernel(const float* __restrict__ clusters,
                                                  int* __restrict__ ids) {
    const int wave = (blockIdx.x * blockDim.x + threadIdx.x) >> 6; // one wave per row
    const int lane = threadIdx.x & 63;
    const float v = clusters[wave * CC + lane];   // CC==64: lane c reads row[c], coalesced
    const unsigned long long m = __ballot(v > 0.5f);
    if (lane == 0) ids[wave] = (int)__builtin_ctzll(m);
}

__global__ __launch_bounds__(256) void circle_main_kernel(
        const float* __restrict__ sim, const int* __restrict__ ids,
        float4* __restrict__ partials) {
    const int b = blockIdx.x;                     // 2048 blocks
    float s_p = 0.f, c_p = 0.f, s_n = 0.f, c_n = 0.f;

    #pragma unroll
    for (int r = 0; r < 2; ++r) {
        const int i = (r == 0) ? b : (NN - 1 - b);   // rows b and 4095-b: 4095 elems total
        const int idi = ids[i];
        const int cstart = (i + 1) >> 2;             // first float4 chunk touching j > i
        const float4* row4 = reinterpret_cast<const float4*>(sim + (size_t)i * NN);
        const int4*   id4p = reinterpret_cast<const int4*>(ids);
        for (int c = cstart + (int)threadIdx.x; c < NN / 4; c += 256) {
            const float4 s4 = row4[c];
            const int4   q4 = id4p[c];
            const float sv[4] = {s4.x, s4.y, s4.z, s4.w};
            const int   jv[4] = {q4.x, q4.y, q4.z, q4.w};
            #pragma unroll
            for (int k = 0; k < 4; ++k) {
                const int   j     = 4 * c + k;
                const bool  valid = (j > i);
                const bool  same  = (jv[k] == idi);
                const float s     = sv[k];
                const float lp = -fmaxf(1.0f + K_MARGIN - s, 0.0f) * (s - (1.0f - K_MARGIN)) * K_GAMMA;
                const float ln =  fmaxf(s + K_MARGIN, 0.0f) * (s - K_MARGIN) * K_GAMMA;
                const float ep = __expf(lp - M_P);
                const float en = __expf(ln - M_N);
                if (valid && same)  { s_p += ep; c_p += 1.0f; }
                if (valid && !same) { s_n += en; c_n += 1.0f; }
            }
        }
    }

    // wave butterfly reduction
    #pragma unroll
    for (int off = 32; off > 0; off >>= 1) {
        s_p += __shfl_xor(s_p, off);
        c_p += __shfl_xor(c_p, off);
        s_n += __shfl_xor(s_n, off);
        c_n += __shfl_xor(c_n, off);
    }
    __shared__ float red[4][4];
    const int wave = threadIdx.x >> 6;
    const int lane = threadIdx.x & 63;
    if (lane == 0) {
        red[wave][0] = s_p; red[wave][1] = c_p;
        red[wave][2] = s_n; red[wave][3] = c_n;
    }
    __syncthreads();
    if (threadIdx.x == 0) {
        float4 p;
        p.x = red[0][0] + red[1][0] + red[2][0] + red[3][0];
        p.y = red[0][1] + red[1][1] + red[2][1] + red[3][1];
        p.z = red[0][2] + red[1][2] + red[2][2] + red[3][2];
        p.w = red[0][3] + red[1][3] + red[2][3] + red[3][3];
        partials[b] = p;
    }
}

__device__ inline float softplus_f(float x) {
    return fmaxf(x, 0.0f) + log1pf(expf(-fabsf(x)));  // -inf -> 0
}

__global__ __launch_bounds__(256) void circle_final_kernel(
        const float4* __restrict__ partials, float* __restrict__ out) {
    float s_p = 0.f, c_p = 0.f, s_n = 0.f, c_n = 0.f;
    for (int k = threadIdx.x; k < 2048; k += 256) {
        const float4 p = partials[k];
        s_p += p.x; c_p += p.y; s_n += p.z; c_n += p.w;
    }
    #pragma unroll
    for (int off = 32; off > 0; off >>= 1) {
        s_p += __shfl_xor(s_p, off);
        c_p += __shfl_xor(c_p, off);
        s_n += __shfl_xor(s_n, off);
        c_n += __shfl_xor(c_n, off);
    }
    __shared__ float red[4][4];
    const int wave = threadIdx.x >> 6;
    const int lane = threadIdx.x & 63;
    if (lane == 0) {
        red[wave][0] = s_p; red[wave][1] = c_p;
        red[wave][2] = s_n; red[wave][3] = c_n;
    }
    __syncthreads();
    if (threadIdx.x == 0) {
        const float S_p = red[0][0] + red[1][0] + red[2][0] + red[3][0];
        const float C_p = red[0][1] + red[1][1] + red[2][1] + red[3][1];
        const float S_n = red[0][2] + red[1][2] + red[2][2] + red[3][2];
        const float C_n = red[0][3] + red[1][3] + red[2][3] + red[3][3];
        const float lse_p = logf(S_p) + M_P;   // -inf if no positive pairs
        const float lse_n = logf(S_n) + M_N;
        const float wp_mean = C_p / fmaxf(C_p, 1.0f);          // prob==1 on positives
        const float wn_mean = 0.0f / fmaxf(C_n, 1.0f);         // prob==0 on negatives
        out[0] = wp_mean * softplus_f(lse_p) + wn_mean * softplus_f(lse_n);
    }
}

extern "C" void kernel_launch(void* const* d_in, const int* in_sizes, int n_in,
                              void* d_out, int out_size, void* d_ws, size_t ws_size,
                              hipStream_t stream) {
    const float* sim      = (const float*)d_in[0];
    const float* clusters = (const float*)d_in[1];
    float*  out      = (float*)d_out;
    int*    ids      = (int*)d_ws;
    float4* partials = (float4*)((char*)d_ws + 16384);

    ids_kernel<<<(NN * CC) / 256, 256, 0, stream>>>(clusters, ids);          // 1024 blocks
    circle_main_kernel<<<NN / 2, 256, 0, stream>>>(sim, ids, partials);      // 2048 blocks
    circle_final_kernel<<<1, 256, 0, stream>>>(partials, out);
}